// Round 7
// baseline (184.931 us; speedup 1.0000x reference)
//
#include <hip/hip_runtime.h>

#define NB      500000
#define HDIM    64
#define OUTC    120           // outputs per chunk (4 MFMA batches of 32: 8 warm + 120 out)
#define NCHUNK  4167          // 4166 full chunks + tail chunk with 80 outputs
#define LDP     68            // padded LDS leading dim: 272 B rows, 16B-aligned, conflict-free b32
#define NLOG2E  (-1.4426950408889634f)
#define NLN2    (-0.6931471805599453f)

typedef _Float16 half_t;
typedef half_t v8h  __attribute__((ext_vector_type(8)));
typedef float  v16f __attribute__((ext_vector_type(16)));

// One wave per chunk; lane j owns hidden channel j in the serial phase.
// Chunk covers serial rows [c*120-8, c*120+120): 8 warm-up (contraction <= 1/4
// per step -> warm error ~1.5e-5) + 120 outputs, as exactly 4 MFMA batches of
// 32. Chunk 0 skips the warm steps (exact zero init).
// B/C operands pre-scaled by -log2e:
//   targ = fma(y_hs, -log2e*wy, a2);  y_hs = rcp(1 + exp2(targ))
// y_h recovered as targ * (-ln2) for the final-state output.
// A-frag: lane holds x[row=tb+(lane&31)][k0..k0+7], k0=(lane>>5)*8.
// B-frag: lane holds Ws[k0..k0+7][(lane&31)+32*tile] (shared k-order with A).
// C/D (verified m74/m101): col=lane&31, row=(r&3)+8*(r>>2)+4*(lane>>5).
// Grid 4167 blocks @ 8.7 KB LDS -> 16.3 blocks/CU < 18-block LDS cap: the
// whole grid is co-resident (single dispatch generation, no ragged tail).
__global__ __launch_bounds__(64)
void ANN_LeafRiver_kernel(const float* __restrict__ x,
                          const float* __restrict__ weight,
                          const float* __restrict__ weight_y,
                          const float* __restrict__ bias,
                          const float* __restrict__ weight_ln,
                          const float* __restrict__ bias_ln,
                          float* __restrict__ out)
{
    __shared__ float buf[32 * LDP];      // 8704 B

    const int lane = threadIdx.x;
    const int c    = blockIdx.x;
    const long base = (long)c * OUTC - 8;    // first serial row of this chunk
    const int half = lane >> 5;
    const int l31  = lane & 31;
    const int k0   = half * 8;

    // B fragments scaled by -log2e
    v8h bf0, bf1;
    #pragma unroll
    for (int j = 0; j < 8; ++j) {
        bf0[j] = (half_t)(weight[(k0 + j) * HDIM + l31]      * NLOG2E);
        bf1[j] = (half_t)(weight[(k0 + j) * HDIM + l31 + 32] * NLOG2E);
    }
    const float wy2 = weight_y[lane] * NLOG2E;
    const float wln = weight_ln[lane];
    const float bln = bias_ln[0];

    v16f cb;                              // scaled bias in the C operand
    {
        const float bsc = bias[0] * NLOG2E;
        #pragma unroll
        for (int r = 0; r < 16; ++r) cb[r] = bsc;
    }

    float y_hs = (c == 0) ? 0.0f : 0.5f;
    float targ = 0.0f;

    float* wb = &buf[(half * 4) * LDP + l31];   // D-write base

    const int nb = (c == NCHUNK - 1) ? 3 : 4;   // tail chunk: 88 rows -> 3 batches

    // load A rows (clamped) for batch bi
    auto loadA = [&](int bi, float4& lo, float4& hi) {
        long t = base + (long)bi * 32 + l31;
        if (t < 0) t = 0;
        if (t >= NB) t = NB - 1;
        const float* xp = x + t * 64 + k0;
        lo = *(const float4*)xp;
        hi = *(const float4*)(xp + 4);
    };

    float4 lo, hi;
    loadA(0, lo, hi);

    #pragma unroll 4
    for (int bi = 0; bi < nb; ++bi) {
        const long tb = base + (long)bi * 32;

        // pack A fragment (RNE scalar casts)
        v8h af;
        af[0] = (half_t)lo.x; af[1] = (half_t)lo.y;
        af[2] = (half_t)lo.z; af[3] = (half_t)lo.w;
        af[4] = (half_t)hi.x; af[5] = (half_t)hi.y;
        af[6] = (half_t)hi.z; af[7] = (half_t)hi.w;

        v16f d0 = __builtin_amdgcn_mfma_f32_32x32x16_f16(af, bf0, cb, 0, 0, 0);
        v16f d1 = __builtin_amdgcn_mfma_f32_32x32x16_f16(af, bf1, cb, 0, 0, 0);

        // D -> LDS (a2[step][channel]); conflict-free b32, imm offsets
        #pragma unroll
        for (int r = 0; r < 16; ++r) {
            const int off = ((r & 3) + 8 * (r >> 2)) * LDP;
            wb[off]      = d0[r];
            wb[off + 32] = d1[r];
        }

        // prefetch next batch's A rows (~900 cyc HBM latency covered)
        if (bi + 1 < nb) loadA(bi + 1, lo, hi);

        __syncthreads();     // single-wave block: compiles to waitcnt only

        // ---- serial recurrence (lane = channel) ----
        if (bi == 0) {
            if (c != 0) {
                #pragma unroll
                for (int s = 0; s < 8; ++s) {          // warm-up: no p-write
                    const float a2 = buf[s * LDP + lane];
                    targ = fmaf(y_hs, wy2, a2);
                    y_hs = __builtin_amdgcn_rcpf(1.0f + __builtin_exp2f(targ));
                }
            }
            #pragma unroll
            for (int s = 8; s < 32; ++s) {
                const float a2 = buf[s * LDP + lane];
                targ = fmaf(y_hs, wy2, a2);
                y_hs = __builtin_amdgcn_rcpf(1.0f + __builtin_exp2f(targ));
                buf[s * LDP + lane] = y_hs * wln;
            }
        } else if (tb + 32 <= NB) {
            #pragma unroll
            for (int s = 0; s < 32; ++s) {
                const float a2 = buf[s * LDP + lane];
                targ = fmaf(y_hs, wy2, a2);
                y_hs = __builtin_amdgcn_rcpf(1.0f + __builtin_exp2f(targ));
                buf[s * LDP + lane] = y_hs * wln;
            }
        } else {                                        // tail batch only
            const int send = (int)(NB - tb);
            for (int s = 0; s < send; ++s) {
                const float a2 = buf[s * LDP + lane];
                targ = fmaf(y_hs, wy2, a2);
                y_hs = __builtin_amdgcn_rcpf(1.0f + __builtin_exp2f(targ));
                buf[s * LDP + lane] = y_hs * wln;
            }
        }
        __syncthreads();

        // ---- batched transposed reduction: lane (r=l31, h=half) sums
        //      row l31, half h via 8x ds_read_b128 (16B-aligned) ----
        {
            const float* rb = &buf[l31 * LDP + half * 32];
            float4 acc0 = ((const float4*)rb)[0];
            float4 acc1 = ((const float4*)rb)[1];
            #pragma unroll
            for (int k = 2; k < 8; k += 2) {
                float4 q0 = ((const float4*)rb)[k];
                float4 q1 = ((const float4*)rb)[k + 1];
                acc0.x += q0.x; acc0.y += q0.y; acc0.z += q0.z; acc0.w += q0.w;
                acc1.x += q1.x; acc1.y += q1.y; acc1.z += q1.z; acc1.w += q1.w;
            }
            float p = (acc0.x + acc0.y) + (acc0.z + acc0.w)
                    + (acc1.x + acc1.y) + (acc1.z + acc1.w);
            p += __shfl_xor(p, 32, 64);
            const long t = tb + l31;
            if (lane < 32 && t < NB && (bi > 0 || l31 >= 8))
                out[t] = bln + p;
        }
        __syncthreads();
    }

    if (c == NCHUNK - 1) {
        out[NB + lane]        = targ * NLN2;   // y_h_f  (t = 499999)
        out[NB + HDIM + lane] = y_hs;          // y_hs_f
    }
}

extern "C" void kernel_launch(void* const* d_in, const int* in_sizes, int n_in,
                              void* d_out, int out_size, void* d_ws, size_t ws_size,
                              hipStream_t stream) {
    const float* x       = (const float*)d_in[0];
    const float* weight  = (const float*)d_in[1];
    const float* wy      = (const float*)d_in[2];
    const float* bias    = (const float*)d_in[3];
    const float* wln     = (const float*)d_in[4];
    const float* bias_ln = (const float*)d_in[5];
    float* out = (float*)d_out;

    ANN_LeafRiver_kernel<<<NCHUNK, 64, 0, stream>>>(x, weight, wy, bias, wln, bias_ln, out);
}

// Round 8
// 179.125 us; speedup vs baseline: 1.0324x; 1.0324x over previous
//
#include <hip/hip_runtime.h>

#define NB      500000
#define HDIM    64
#define OUTC    88            // outputs per chunk
#define NCHUNK  5682          // ceil(NB/OUTC); last chunk outputs 72
#define LDP     65            // padded LDS leading dim -> conflict-free
#define NLOG2E  (-1.4426950408889634f)
#define NLN2    (-0.6931471805599453f)

typedef _Float16 half_t;
typedef half_t v8h  __attribute__((ext_vector_type(8)));
typedef float  v16f __attribute__((ext_vector_type(16)));

// One wave per chunk; lane j owns hidden channel j in the serial phase.
// Chunk covers serial steps [c*88-8, c*88+88): 8 warm-up (contraction <= 1/4
// per step -> warm error ~1.5e-5) + 88 outputs, as exactly 3 MFMA batches of
// 32 (no dedicated warm-up batch). Chunk 0 skips the warm steps (exact init).
// B/C operands pre-scaled by -log2e so the serial step needs no extra mul:
//   targ = fma(y_hs, -log2e*wy, a2);  y_hs = rcp(1 + exp2(targ))
// y_h recovered as targ * (-ln2) for the final-state output.
// A-frag: lane holds x[row=tb+(lane&31)][k0..k0+7], k0=(lane>>5)*8.
// B-frag: lane holds Ws[k0..k0+7][(lane&31)+32*tile] (shared k-order with A).
// C/D (verified m74/m101): col=lane&31, row=(r&3)+8*(r>>2)+4*(lane>>5).
__global__ __launch_bounds__(64)
void ANN_LeafRiver_kernel(const float* __restrict__ x,
                          const float* __restrict__ weight,
                          const float* __restrict__ weight_y,
                          const float* __restrict__ bias,
                          const float* __restrict__ weight_ln,
                          const float* __restrict__ bias_ln,
                          float* __restrict__ out)
{
    __shared__ float buf[32 * LDP];      // 8.32 KB

    const int lane = threadIdx.x;
    const int c    = blockIdx.x;
    const long base = (long)c * OUTC - 8;    // first serial row of this chunk
    const int half = lane >> 5;
    const int l31  = lane & 31;
    const int k0   = half * 8;

    // B fragments scaled by -log2e
    v8h bf0, bf1;
    #pragma unroll
    for (int j = 0; j < 8; ++j) {
        bf0[j] = (half_t)(weight[(k0 + j) * HDIM + l31]      * NLOG2E);
        bf1[j] = (half_t)(weight[(k0 + j) * HDIM + l31 + 32] * NLOG2E);
    }
    const float wy2 = weight_y[lane] * NLOG2E;
    const float wln = weight_ln[lane];
    const float bln = bias_ln[0];

    v16f cb;                              // scaled bias in the C operand
    {
        const float bsc = bias[0] * NLOG2E;
        #pragma unroll
        for (int r = 0; r < 16; ++r) cb[r] = bsc;
    }

    float y_hs = (c == 0) ? 0.0f : 0.5f;
    float targ = 0.0f;

    float* wb = &buf[(half * 4) * LDP + l31];   // D-write base

    // helper: load A rows (clamped) for batch bi
    auto loadA = [&](int bi, float4& lo, float4& hi) {
        long t = base + (long)bi * 32 + l31;
        if (t < 0) t = 0;
        if (t >= NB) t = NB - 1;
        const float* xp = x + t * 64 + k0;
        lo = *(const float4*)xp;
        hi = *(const float4*)(xp + 4);
    };

    float4 lo, hi;
    loadA(0, lo, hi);

    #pragma unroll
    for (int bi = 0; bi < 3; ++bi) {
        const long tb = base + bi * 32;

        // pack A fragment (RNE scalar casts -> v_cvt_f16_f32)
        v8h af;
        af[0] = (half_t)lo.x; af[1] = (half_t)lo.y;
        af[2] = (half_t)lo.z; af[3] = (half_t)lo.w;
        af[4] = (half_t)hi.x; af[5] = (half_t)hi.y;
        af[6] = (half_t)hi.z; af[7] = (half_t)hi.w;

        v16f d0 = __builtin_amdgcn_mfma_f32_32x32x16_f16(af, bf0, cb, 0, 0, 0);
        v16f d1 = __builtin_amdgcn_mfma_f32_32x32x16_f16(af, bf1, cb, 0, 0, 0);

        // D -> LDS (a2[step][channel]); imm-offset ds_writes off one base reg
        #pragma unroll
        for (int r = 0; r < 16; ++r) {
            const int off = ((r & 3) + 8 * (r >> 2)) * LDP;
            wb[off]      = d0[r];
            wb[off + 32] = d1[r];
        }

        // prefetch next batch's A rows: ~950 cyc of serial work covers HBM
        if (bi < 2) loadA(bi + 1, lo, hi);

        __syncthreads();

        // ---- serial recurrence (lane = channel) ----
        if (bi == 0) {
            if (c != 0) {
                #pragma unroll
                for (int s = 0; s < 8; ++s) {          // warm-up: no p-write
                    const float a2 = buf[s * LDP + lane];
                    targ = fmaf(y_hs, wy2, a2);
                    y_hs = __builtin_amdgcn_rcpf(1.0f + __builtin_exp2f(targ));
                }
            }
            #pragma unroll
            for (int s = 8; s < 32; ++s) {
                const float a2 = buf[s * LDP + lane];
                targ = fmaf(y_hs, wy2, a2);
                y_hs = __builtin_amdgcn_rcpf(1.0f + __builtin_exp2f(targ));
                buf[s * LDP + lane] = y_hs * wln;
            }
        } else if (tb + 32 <= NB) {
            #pragma unroll
            for (int s = 0; s < 32; ++s) {
                const float a2 = buf[s * LDP + lane];
                targ = fmaf(y_hs, wy2, a2);
                y_hs = __builtin_amdgcn_rcpf(1.0f + __builtin_exp2f(targ));
                buf[s * LDP + lane] = y_hs * wln;
            }
        } else {                                        // tail (1 chunk only)
            const int send = (int)(NB - tb);
            for (int s = 0; s < send; ++s) {
                const float a2 = buf[s * LDP + lane];
                targ = fmaf(y_hs, wy2, a2);
                y_hs = __builtin_amdgcn_rcpf(1.0f + __builtin_exp2f(targ));
                buf[s * LDP + lane] = y_hs * wln;
            }
        }
        __syncthreads();

        // ---- batched transposed reduction: lane (r=l31, h=half) ----
        {
            const float* rb = &buf[l31 * LDP + half * 32];
            float p = 0.0f;
            #pragma unroll
            for (int k = 0; k < 32; ++k) p += rb[k];    // conflict-free
            p += __shfl_xor(p, 32, 64);
            const long t = tb + l31;
            if (lane < 32 && t < NB && (bi > 0 || l31 >= 8))
                out[t] = bln + p;
        }
        __syncthreads();
    }

    if (c == NCHUNK - 1) {
        out[NB + lane]        = targ * NLN2;   // y_h_f  (t = 499999)
        out[NB + HDIM + lane] = y_hs;          // y_hs_f
    }
}

extern "C" void kernel_launch(void* const* d_in, const int* in_sizes, int n_in,
                              void* d_out, int out_size, void* d_ws, size_t ws_size,
                              hipStream_t stream) {
    const float* x       = (const float*)d_in[0];
    const float* weight  = (const float*)d_in[1];
    const float* wy      = (const float*)d_in[2];
    const float* bias    = (const float*)d_in[3];
    const float* wln     = (const float*)d_in[4];
    const float* bias_ln = (const float*)d_in[5];
    float* out = (float*)d_out;

    ANN_LeafRiver_kernel<<<NCHUNK, 64, 0, stream>>>(x, weight, wy, bias, wln, bias_ln, out);
}